// Round 1
// baseline (63.562 us; speedup 1.0000x reference)
//
#include <hip/hip_runtime.h>
#include <math.h>

#define NL 16

// M = R7(a2) @ R5(a1) @ R2(a0), all real SO(3) rotations:
//  row0 = [ c1*c0,              c1*s0,              s1    ]
//  row1 = [-c2*s0 - s2*s1*c0,   c2*c0 - s2*s1*s0,   s2*c1 ]
//  row2 = [ s2*s0 - c2*s1*c0,  -s2*c0 - c2*s1*s0,   c2*c1 ]

__global__ __launch_bounds__(256) void qnn_kernel(
    const float* __restrict__ batch,
    const float* __restrict__ weights,
    float* __restrict__ out,
    int nquads)
{
    __shared__ float4 Vs[NL][3];   // row r of V_l in .x/.y/.z

    if (threadIdx.x < NL) {
        const int l = threadIdx.x;
        float a0 = weights[l * 6 + 0];
        float a1 = weights[l * 6 + 1];
        float a2 = weights[l * 6 + 2];
        float s0, c0, s1, c1, s2, c2;
        __sincosf(a0, &s0, &c0);
        __sincosf(a1, &s1, &c1);
        __sincosf(a2, &s2, &c2);
        Vs[l][0] = make_float4(c1 * c0, c1 * s0, s1, 0.f);
        Vs[l][1] = make_float4(-c2 * s0 - s2 * s1 * c0, c2 * c0 - s2 * s1 * s0, s2 * c1, 0.f);
        Vs[l][2] = make_float4(s2 * s0 - c2 * s1 * c0, -s2 * c0 - c2 * s1 * s0, c2 * c1, 0.f);
    }
    __syncthreads();

    const int t = blockIdx.x * blockDim.x + threadIdx.x;   // quad index (4 samples)
    if (t >= nquads) return;

    const float4* __restrict__ b4 = (const float4*)batch;
    float4 q0 = b4[3 * t + 0];
    float4 q1 = b4[3 * t + 1];
    float4 q2 = b4[3 * t + 2];

    float xs[4][3] = {
        {q0.x, q0.y, q0.z},
        {q0.w, q1.x, q1.y},
        {q1.z, q1.w, q2.x},
        {q2.y, q2.z, q2.w},
    };

    float U[4][9];
    float S0[4], S1[4], S2[4];
    #pragma unroll
    for (int i = 0; i < 4; i++) {
        float s0, c0, s1, c1, s2, c2;
        __sincosf(xs[i][0], &s0, &c0);
        __sincosf(xs[i][1], &s1, &c1);
        __sincosf(xs[i][2], &s2, &c2);
        U[i][0] = c1 * c0;                  U[i][1] = c1 * s0;                  U[i][2] = s1;
        U[i][3] = -c2 * s0 - s2 * s1 * c0;  U[i][4] = c2 * c0 - s2 * s1 * s0;   U[i][5] = s2 * c1;
        U[i][6] = s2 * s0 - c2 * s1 * c0;   U[i][7] = -s2 * c0 - c2 * s1 * s0;  U[i][8] = c2 * c1;
        S0[i] = 1.f; S1[i] = 0.f; S2[i] = 0.f;
    }

    #pragma unroll
    for (int l = 0; l < NL; l++) {
        float4 r0 = Vs[l][0];
        float4 r1 = Vs[l][1];
        float4 r2 = Vs[l][2];
        #pragma unroll
        for (int i = 0; i < 4; i++) {
            float t0 = U[i][0] * S0[i] + U[i][1] * S1[i] + U[i][2] * S2[i];
            float t1 = U[i][3] * S0[i] + U[i][4] * S1[i] + U[i][5] * S2[i];
            float t2 = U[i][6] * S0[i] + U[i][7] * S1[i] + U[i][8] * S2[i];
            S0[i] = r0.x * t0 + r0.y * t1 + r0.z * t2;
            S1[i] = r1.x * t0 + r1.y * t1 + r1.z * t2;
            S2[i] = r2.x * t0 + r2.y * t1 + r2.z * t2;
        }
    }

    // fid_k = (sqrt(max(|s_k|^2, 1e-10)) + 2*sqrt(1e-10))^2
    //       = (max(|s_k|, 1e-5) + 2e-5)^2 ; out = fid / sum(fid)
    float ov[12];
    #pragma unroll
    for (int i = 0; i < 4; i++) {
        float f0 = fmaxf(fabsf(S0[i]), 1e-5f) + 2e-5f; f0 *= f0;
        float f1 = fmaxf(fabsf(S1[i]), 1e-5f) + 2e-5f; f1 *= f1;
        float f2 = fmaxf(fabsf(S2[i]), 1e-5f) + 2e-5f; f2 *= f2;
        float inv = __builtin_amdgcn_rcpf(f0 + f1 + f2);
        ov[3 * i + 0] = f0 * inv;
        ov[3 * i + 1] = f1 * inv;
        ov[3 * i + 2] = f2 * inv;
    }
    float4* __restrict__ o4 = (float4*)out;
    o4[3 * t + 0] = make_float4(ov[0], ov[1], ov[2],  ov[3]);
    o4[3 * t + 1] = make_float4(ov[4], ov[5], ov[6],  ov[7]);
    o4[3 * t + 2] = make_float4(ov[8], ov[9], ov[10], ov[11]);
}

extern "C" void kernel_launch(void* const* d_in, const int* in_sizes, int n_in,
                              void* d_out, int out_size, void* d_ws, size_t ws_size,
                              hipStream_t stream) {
    const float* batch   = (const float*)d_in[0];   // [B,3] fp32
    const float* weights = (const float*)d_in[1];   // [16,6] fp32
    float* out = (float*)d_out;                     // [B,3] fp32

    const int B = in_sizes[0] / 3;                  // 524288
    const int nquads = B / 4;                       // B divisible by 4
    const int block = 256;
    const int grid = (nquads + block - 1) / block;  // 512 blocks

    qnn_kernel<<<grid, block, 0, stream>>>(batch, weights, out, nquads);
}

// Round 2
// 62.335 us; speedup vs baseline: 1.0197x; 1.0197x over previous
//
#include <hip/hip_runtime.h>
#include <math.h>

#define NL 16

typedef float v2f __attribute__((ext_vector_type(2)));

// R(gm2,a)/R(gm5,a)/R(gm7,a) are real SO(3) plane rotations; the composed
// per-angle-triple matrix M = R7(a2) @ R5(a1) @ R2(a0) is:
//  row0 = [ c1*c0,              c1*s0,              s1    ]
//  row1 = [-c2*s0 - s2*s1*c0,   c2*c0 - s2*s1*s0,   s2*c1 ]
//  row2 = [ s2*s0 - c2*s1*c0,  -s2*c0 - c2*s1*s0,   c2*c1 ]
// Initial state e0 is real -> whole circuit is real 3-vector math.

__global__ __launch_bounds__(256) void qnn_kernel(
    const float* __restrict__ batch,
    const float* __restrict__ weights,
    float* __restrict__ out,
    int nquads)
{
    __shared__ float4 Vs[NL][3];   // row r of V_l in .x/.y/.z

    if (threadIdx.x < NL) {
        const int l = threadIdx.x;
        float a0 = weights[l * 6 + 0];
        float a1 = weights[l * 6 + 1];
        float a2 = weights[l * 6 + 2];
        float s0, c0, s1, c1, s2, c2;
        __sincosf(a0, &s0, &c0);
        __sincosf(a1, &s1, &c1);
        __sincosf(a2, &s2, &c2);
        Vs[l][0] = make_float4(c1 * c0, c1 * s0, s1, 0.f);
        Vs[l][1] = make_float4(-c2 * s0 - s2 * s1 * c0, c2 * c0 - s2 * s1 * s0, s2 * c1, 0.f);
        Vs[l][2] = make_float4(s2 * s0 - c2 * s1 * c0, -s2 * c0 - c2 * s1 * s0, c2 * c1, 0.f);
    }
    __syncthreads();

    const int t = blockIdx.x * blockDim.x + threadIdx.x;   // quad index (4 samples)
    if (t >= nquads) return;

    const float4* __restrict__ b4 = (const float4*)batch;
    float4 q0 = b4[3 * t + 0];
    float4 q1 = b4[3 * t + 1];
    float4 q2 = b4[3 * t + 2];

    const float xs[4][3] = {
        {q0.x, q0.y, q0.z},
        {q0.w, q1.x, q1.y},
        {q1.z, q1.w, q2.x},
        {q2.y, q2.z, q2.w},
    };

    // Build per-sample encoding matrices, then pack sample pairs into float2
    // lanes so the 16-layer chain runs on v_pk_fma_f32 (dual fp32 FMA).
    float Usc[4][9];
    #pragma unroll
    for (int i = 0; i < 4; i++) {
        float s0, c0, s1, c1, s2, c2;
        __sincosf(xs[i][0], &s0, &c0);
        __sincosf(xs[i][1], &s1, &c1);
        __sincosf(xs[i][2], &s2, &c2);
        Usc[i][0] = c1 * c0;                   Usc[i][1] = c1 * s0;                   Usc[i][2] = s1;
        Usc[i][3] = -c2 * s0 - s2 * s1 * c0;   Usc[i][4] = c2 * c0 - s2 * s1 * s0;    Usc[i][5] = s2 * c1;
        Usc[i][6] = s2 * s0 - c2 * s1 * c0;    Usc[i][7] = -s2 * c0 - c2 * s1 * s0;   Usc[i][8] = c2 * c1;
    }

    v2f U2[2][9];
    v2f S0[2], S1[2], S2[2];
    #pragma unroll
    for (int p = 0; p < 2; p++) {
        #pragma unroll
        for (int k = 0; k < 9; k++) {
            v2f u; u.x = Usc[2 * p][k]; u.y = Usc[2 * p + 1][k];
            U2[p][k] = u;
        }
        v2f one; one.x = 1.f; one.y = 1.f;
        v2f zero; zero.x = 0.f; zero.y = 0.f;
        S0[p] = one; S1[p] = zero; S2[p] = zero;
    }

    #pragma unroll
    for (int l = 0; l < NL; l++) {
        const float4 r0 = Vs[l][0];
        const float4 r1 = Vs[l][1];
        const float4 r2 = Vs[l][2];
        #pragma unroll
        for (int p = 0; p < 2; p++) {
            v2f t0 = U2[p][0] * S0[p] + U2[p][1] * S1[p] + U2[p][2] * S2[p];
            v2f t1 = U2[p][3] * S0[p] + U2[p][4] * S1[p] + U2[p][5] * S2[p];
            v2f t2 = U2[p][6] * S0[p] + U2[p][7] * S1[p] + U2[p][8] * S2[p];
            S0[p] = r0.x * t0 + r0.y * t1 + r0.z * t2;
            S1[p] = r1.x * t0 + r1.y * t1 + r1.z * t2;
            S2[p] = r2.x * t0 + r2.y * t1 + r2.z * t2;
        }
    }

    // fid_k = (max(|s_k|, 1e-5) + 2e-5)^2 ; out = fid / sum(fid)
    float ov[12];
    #pragma unroll
    for (int p = 0; p < 2; p++) {
        #pragma unroll
        for (int h = 0; h < 2; h++) {
            const int i = 2 * p + h;
            float a0 = h ? S0[p].y : S0[p].x;
            float a1 = h ? S1[p].y : S1[p].x;
            float a2 = h ? S2[p].y : S2[p].x;
            float f0 = fmaxf(fabsf(a0), 1e-5f) + 2e-5f; f0 *= f0;
            float f1 = fmaxf(fabsf(a1), 1e-5f) + 2e-5f; f1 *= f1;
            float f2 = fmaxf(fabsf(a2), 1e-5f) + 2e-5f; f2 *= f2;
            float inv = __builtin_amdgcn_rcpf(f0 + f1 + f2);
            ov[3 * i + 0] = f0 * inv;
            ov[3 * i + 1] = f1 * inv;
            ov[3 * i + 2] = f2 * inv;
        }
    }
    float4* __restrict__ o4 = (float4*)out;
    o4[3 * t + 0] = make_float4(ov[0], ov[1], ov[2],  ov[3]);
    o4[3 * t + 1] = make_float4(ov[4], ov[5], ov[6],  ov[7]);
    o4[3 * t + 2] = make_float4(ov[8], ov[9], ov[10], ov[11]);
}

extern "C" void kernel_launch(void* const* d_in, const int* in_sizes, int n_in,
                              void* d_out, int out_size, void* d_ws, size_t ws_size,
                              hipStream_t stream) {
    const float* batch   = (const float*)d_in[0];   // [B,3] fp32
    const float* weights = (const float*)d_in[1];   // [16,6] fp32
    float* out = (float*)d_out;                     // [B,3] fp32

    const int B = in_sizes[0] / 3;                  // 524288
    const int nquads = B / 4;
    const int block = 256;
    const int grid = (nquads + block - 1) / block;  // 512 blocks

    qnn_kernel<<<grid, block, 0, stream>>>(batch, weights, out, nquads);
}